// Round 11
// baseline (226.756 us; speedup 1.0000x reference)
//
#include <hip/hip_runtime.h>
#include <hip/hip_bf16.h>

// NVFP4 dynamic linear: x[2,2048,4096] f32, w[4096,4096] f32, bias[4096] -> out f32
// M=4096, N=4096, K=4096.
//
// amax -> fused coalesced quant/dequant to bf16 (exact: e2m1 x e4m3 fits
// bf16) -> 256x256 bf16 MFMA GEMM on the round-8 chassis (ring-4 LDS,
// BK=32, 2-tile groups, counted vmcnt(8), T1/T2/T5) but with the
// 32x32x16 MFMA shape (2495 TF ubench vs 2075 for 16x16x32; 4x fewer
// MFMA instructions, same LDS traffic).
//
// ws: [0,8) amax bits | [256, +32MB) dx bf16 | [+32MB) dw bf16

typedef unsigned short u16;
typedef __bf16 bf16x8 __attribute__((ext_vector_type(8)));
typedef float f32x16 __attribute__((ext_vector_type(16)));

#define GLD_LDS(gsrc, ldst)                                                     \
  __builtin_amdgcn_global_load_lds(                                             \
      (const __attribute__((address_space(1))) void*)(gsrc),                    \
      (__attribute__((address_space(3))) void*)(ldst), 16, 0, 0)

#define SBAR()                                                                  \
  do {                                                                          \
    asm volatile("" ::: "memory");                                              \
    __builtin_amdgcn_s_barrier();                                               \
    asm volatile("" ::: "memory");                                              \
  } while (0)

#define KEEP4(S) asm volatile("" ::"v"(S[0]), "v"(S[1]), "v"(S[2]), "v"(S[3]))

// ---------------- rounding helpers (bit-exact vs numpy RTNE) -----------------

__device__ __forceinline__ float round_e4m3(float v) {
  if (v < 0.015625f) {                        // subnormal grid, step 2^-9
    return rintf(v * 512.0f) * 0.001953125f;
  }
  unsigned b = __float_as_uint(v);
  unsigned e = (b >> 23) & 0xFFu;
  float step = __uint_as_float((e - 3u) << 23); // 2^(e-127-3)
  return rintf(v / step) * step;
}

__device__ __forceinline__ float round_e2m1(float v) {
  float a = fabsf(v);
  float step = (a < 2.0f) ? 0.5f : ((a < 4.0f) ? 1.0f : 2.0f);
  float q = fminf(rintf(a / step) * step, 6.0f);
  return copysignf(q, v);
}

// ---------------- kernel 1: global amax of |x| and |w| ----------------------

__global__ void nvfp4_amax_kernel(const float* __restrict__ x,
                                  const float* __restrict__ w,
                                  unsigned* __restrict__ sc, int nx4, int nw4) {
  const float4* src = blockIdx.y ? (const float4*)w : (const float4*)x;
  int n4 = blockIdx.y ? nw4 : nx4;
  float m = 0.f;
  for (int i = blockIdx.x * blockDim.x + threadIdx.x; i < n4;
       i += gridDim.x * blockDim.x) {
    float4 v = src[i];
    m = fmaxf(m, fmaxf(fmaxf(fabsf(v.x), fabsf(v.y)),
                       fmaxf(fabsf(v.z), fabsf(v.w))));
  }
#pragma unroll
  for (int off = 32; off; off >>= 1) m = fmaxf(m, __shfl_down(m, off));
  __shared__ float red[4];
  if ((threadIdx.x & 63) == 0) red[threadIdx.x >> 6] = m;
  __syncthreads();
  if (threadIdx.x == 0) {
    m = fmaxf(fmaxf(red[0], red[1]), fmaxf(red[2], red[3]));
    atomicMax(&sc[blockIdx.y], __float_as_uint(m));
  }
}

// ------------- kernel 2: fused coalesced quantize->dequantize ---------------

__global__ void nvfp4_quant_kernel(const float* __restrict__ x,
                                   const float* __restrict__ w,
                                   u16* __restrict__ dx, u16* __restrict__ dw,
                                   const unsigned* __restrict__ sc,
                                   int nx4, int nw4) {
  int g = blockIdx.x * blockDim.x + threadIdx.x;   // global float4 index
  const float* src; u16* dst; int which, i4;
  if (g < nx4) { src = x; dst = dx; which = 0; i4 = g; }
  else {
    i4 = g - nx4; if (i4 >= nw4) return;
    src = w; dst = dw; which = 1;
  }
  float4 v = ((const float4*)src)[i4];

  float m = fmaxf(fmaxf(fabsf(v.x), fabsf(v.y)), fmaxf(fabsf(v.z), fabsf(v.w)));
  m = fmaxf(m, __shfl_xor(m, 1));                  // 4-lane group = 16-elem block
  m = fmaxf(m, __shfl_xor(m, 2));

  float amax = fmaxf(__uint_as_float(sc[which]), 1e-12f);
  float gs = 2688.0f / amax;
  float sf = round_e4m3((m * gs) / 6.0f);
  float sfs = fmaxf(sf, 1e-12f);
  float r = gs / sfs;

  ushort4 o;
  o.x = (u16)(__float_as_uint(round_e2m1(v.x * r) * sf) >> 16);
  o.y = (u16)(__float_as_uint(round_e2m1(v.y * r) * sf) >> 16);
  o.z = (u16)(__float_as_uint(round_e2m1(v.z * r) * sf) >> 16);
  o.w = (u16)(__float_as_uint(round_e2m1(v.w * r) * sf) >> 16);
  ((ushort4*)dst)[i4] = o;                         // 8B coalesced
}

// ---------------- kernel 4: 256x256 bf16 GEMM, 32x32x16 MFMA ---------------
// 512 threads = 8 waves (2M x 4N), per-wave 128x64 = acc[4][2] of f32x16.
// BK=32, ring-4 LDS, group = 2 K-tiles = 4 phases (r8 chassis):
//  P0: read bv(4)+av(mt0-1,4); STAGE_A(s0); bar; 8 MFMA; bar
//  P1: read aw(mt2-3,4);       STAGE_B(s0); bar; 8 MFMA; vmcnt(8); bar
//  P2/P3: same for tile t1 with bvo.
// Frag k-map (A and B symmetric): row/col = lane&31, k = (lane>>5)*8 + j,
// kst selects k 0-15 / 16-31. LDS swizzle: slot' = slot ^ (row&3)
// (uniform bank load for 32-lane row-span reads); same involution on the
// staging global source.

#define BM 256
#define BN 256
#define BK 32

__global__ __launch_bounds__(512, 2) void nvfp4_gemm_kernel(
    const u16* __restrict__ A,   // dx [M][K]
    const u16* __restrict__ B,   // dw [N][K]
    const float* __restrict__ bias, const unsigned* __restrict__ sc,
    float* __restrict__ C, int M, int N, int K) {
  __shared__ u16 lA[4][BM * BK];
  __shared__ u16 lB[4][BN * BK];

  const int tid = threadIdx.x;
  const int lane = tid & 63;
  const int wv = tid >> 6;
  const int wm = wv >> 2;        // 0..1
  const int wn = wv & 3;         // 0..3

  // T1: XCD-aware swizzle (256 blocks, 8 XCDs x 32; 4x8 tile region per XCD)
  const int bid = blockIdx.x;
  const int xcd = bid & 7, loc = bid >> 3;
  const int tm0 = ((xcd & 3) * 4 + (loc & 3)) * BM;
  const int tn0 = ((xcd >> 2) * 8 + (loc >> 2)) * BN;

  // ---- staging addressing (pre-swizzled global source, linear LDS dest) ----
  const int srow = tid >> 2;                 // 0..127
  const int scol = ((tid & 3) ^ (srow & 3)) * 8;   // swizzled 8-elem slot
  const u16* gA0 = A + (size_t)(tm0 + srow) * K + scol;
  const u16* gA1 = A + (size_t)(tm0 + 128 + srow) * K + scol;   // (row+128)&3 same
  const u16* gB0 = B + (size_t)(tn0 + srow) * K + scol;
  const u16* gB1 = B + (size_t)(tn0 + 128 + srow) * K + scol;
  const int ld0 = tid * 8;
  const int ld1 = tid * 8 + 4096;

#define STAGE_A(tt)                                                             \
  do {                                                                          \
    int _b = (tt) & 3;                                                          \
    GLD_LDS(gA0 + (size_t)(tt) * BK, &lA[_b][ld0]);                             \
    GLD_LDS(gA1 + (size_t)(tt) * BK, &lA[_b][ld1]);                             \
  } while (0)
#define STAGE_B(tt)                                                             \
  do {                                                                          \
    int _b = (tt) & 3;                                                          \
    GLD_LDS(gB0 + (size_t)(tt) * BK, &lB[_b][ld0]);                             \
    GLD_LDS(gB1 + (size_t)(tt) * BK, &lB[_b][ld1]);                             \
  } while (0)

  // ---- fragment addressing (slot' = slot ^ (row&3), same involution) -------
  const int l31 = lane & 31;
  const int kq = lane >> 5;                        // k-quarter within kst
  const int key = lane & 3;                        // row&3 == lane&3
  const int cc0 = ((0 * 2 + kq) ^ key) * 8;        // kst=0 slot
  const int cc1 = ((1 * 2 + kq) ^ key) * 8;        // kst=1 slot
  const int arow = wm * 128 + l31;                 // + mt*32
  const int brow = wn * 64 + l31;                  // + nt*32

  f32x16 acc[4][2] = {};                           // [mt][nt]
  const int NT = K / BK;                           // 128
  const int NG = NT / 2;                           // 64 groups of 2 tiles

  // prologue: stage tiles 0,1,2 (12 loads); vmcnt(8) -> tile 0 resident
  STAGE_A(0); STAGE_B(0);
  STAGE_A(1); STAGE_B(1);
  STAGE_A(2); STAGE_B(2);
  asm volatile("s_waitcnt vmcnt(8)" ::: "memory");
  SBAR();

  bf16x8 av[4], aw[4], bve[4], bvo[4];   // [mt or nt][kst] flattened idx*2+kst

#define READ_AF(DST, buf, mtbase)                                               \
  do {                                                                          \
    DST[0] = *(const bf16x8*)((buf) + (arow + (mtbase) * 32) * BK + cc0);       \
    DST[1] = *(const bf16x8*)((buf) + (arow + (mtbase) * 32) * BK + cc1);       \
    DST[2] = *(const bf16x8*)((buf) + (arow + (mtbase) * 32 + 32) * BK + cc0);  \
    DST[3] = *(const bf16x8*)((buf) + (arow + (mtbase) * 32 + 32) * BK + cc1);  \
  } while (0)
#define READ_BF(DST, buf)                                                       \
  do {                                                                          \
    DST[0] = *(const bf16x8*)((buf) + (brow) * BK + cc0);                       \
    DST[1] = *(const bf16x8*)((buf) + (brow) * BK + cc1);                       \
    DST[2] = *(const bf16x8*)((buf) + (brow + 32) * BK + cc0);                  \
    DST[3] = *(const bf16x8*)((buf) + (brow + 32) * BK + cc1);                  \
  } while (0)

  // 8 MFMA: acc[a0+.][nt] over mt pair x nt pair x kst chain
#define MFMA8(AF, BF, a0)                                                       \
  do {                                                                          \
    acc[a0][0]     = __builtin_amdgcn_mfma_f32_32x32x16_bf16(AF[0], BF[0], acc[a0][0], 0, 0, 0);     \
    acc[a0][1]     = __builtin_amdgcn_mfma_f32_32x32x16_bf16(AF[0], BF[2], acc[a0][1], 0, 0, 0);     \
    acc[a0 + 1][0] = __builtin_amdgcn_mfma_f32_32x32x16_bf16(AF[2], BF[0], acc[a0 + 1][0], 0, 0, 0); \
    acc[a0 + 1][1] = __builtin_amdgcn_mfma_f32_32x32x16_bf16(AF[2], BF[2], acc[a0 + 1][1], 0, 0, 0); \
    acc[a0][0]     = __builtin_amdgcn_mfma_f32_32x32x16_bf16(AF[1], BF[1], acc[a0][0], 0, 0, 0);     \
    acc[a0][1]     = __builtin_amdgcn_mfma_f32_32x32x16_bf16(AF[1], BF[3], acc[a0][1], 0, 0, 0);     \
    acc[a0 + 1][0] = __builtin_amdgcn_mfma_f32_32x32x16_bf16(AF[3], BF[1], acc[a0 + 1][0], 0, 0, 0); \
    acc[a0 + 1][1] = __builtin_amdgcn_mfma_f32_32x32x16_bf16(AF[3], BF[3], acc[a0 + 1][1], 0, 0, 0); \
  } while (0)

  for (int g = 0; g < NG; ++g) {
    const int t0 = 2 * g, t1 = 2 * g + 1;
    const int s0 = 2 * g + 3, s1 = 2 * g + 4;  // tiles staged this group
    const u16* bufA0 = lA[t0 & 3];
    const u16* bufB0 = lB[t0 & 3];
    const u16* bufA1 = lA[t1 & 3];
    const u16* bufB1 = lB[t1 & 3];

    // ---------------- P0: tile t0, mt 0-1 ----------------------------------
    READ_BF(bve, bufB0);
    READ_AF(av, bufA0, 0);
    if (s0 < NT) STAGE_A(s0);
    SBAR();
    __builtin_amdgcn_s_setprio(1);
    MFMA8(av, bve, 0);
    __builtin_amdgcn_s_setprio(0);
    SBAR();

    // ---------------- P1: tile t0, mt 2-3 ----------------------------------
    READ_AF(aw, bufA0, 2);
    if (s0 < NT) STAGE_B(s0);
    SBAR();
    __builtin_amdgcn_s_setprio(1);
    MFMA8(aw, bve, 2);
    __builtin_amdgcn_s_setprio(0);
    KEEP4(av);
    if (g < NG - 1) asm volatile("s_waitcnt vmcnt(8)" ::: "memory");
    else            asm volatile("s_waitcnt vmcnt(0)" ::: "memory");
    SBAR();

    // ---------------- P2: tile t1, mt 0-1 ----------------------------------
    READ_BF(bvo, bufB1);
    READ_AF(av, bufA1, 0);
    if (s1 < NT) STAGE_A(s1);
    SBAR();
    __builtin_amdgcn_s_setprio(1);
    MFMA8(av, bvo, 0);
    __builtin_amdgcn_s_setprio(0);
    SBAR();

    // ---------------- P3: tile t1, mt 2-3 ----------------------------------
    READ_AF(aw, bufA1, 2);
    if (s1 < NT) STAGE_B(s1);
    SBAR();
    __builtin_amdgcn_s_setprio(1);
    MFMA8(aw, bvo, 2);
    __builtin_amdgcn_s_setprio(0);
    KEEP4(bve);
    KEEP4(av);
    KEEP4(aw);
    if (g < NG - 2)       asm volatile("s_waitcnt vmcnt(8)" ::: "memory");
    else if (g == NG - 2) asm volatile("s_waitcnt vmcnt(4)" ::: "memory");
    SBAR();
  }

  // ---------------- epilogue: out = alpha*acc + bias ------------------------
  // 32x32 C/D layout [m74/m101]: col = lane&31, row = (reg&3)+8*(reg>>2)+4*(lane>>5)
  float ax = fmaxf(__uint_as_float(sc[0]), 1e-12f);
  float aw_ = fmaxf(__uint_as_float(sc[1]), 1e-12f);
  float alpha = (ax * aw_) / 7225344.0f;           // amax_x*amax_w / 2688^2

#pragma unroll
  for (int mt = 0; mt < 4; ++mt) {
#pragma unroll
    for (int nt = 0; nt < 2; ++nt) {
      int col = tn0 + wn * 64 + nt * 32 + l31;
      float bvv = bias[col];
#pragma unroll
      for (int reg = 0; reg < 16; ++reg) {
        int row = tm0 + wm * 128 + mt * 32 + (reg & 3) + 8 * (reg >> 2) + 4 * kq;
        C[(size_t)row * N + col] = alpha * acc[mt][nt][reg] + bvv;
      }
    }
  }
#undef STAGE_A
#undef STAGE_B
#undef READ_AF
#undef READ_BF
#undef MFMA8
}

// ---------------------------------------------------------------------------

extern "C" void kernel_launch(void* const* d_in, const int* in_sizes, int n_in,
                              void* d_out, int out_size, void* d_ws, size_t ws_size,
                              hipStream_t stream) {
  const float* x = (const float*)d_in[0];
  const float* w = (const float*)d_in[1];
  const float* bias = (const float*)d_in[2];
  float* out = (float*)d_out;

  const int N = in_sizes[2];
  const int K = in_sizes[1] / N;
  const int M = in_sizes[0] / K;

  unsigned char* ws = (unsigned char*)d_ws;
  unsigned* sc = (unsigned*)ws;
  u16* dx = (u16*)(ws + 256);
  u16* dw = (u16*)(ws + 256 + (size_t)M * K * sizeof(u16));

  hipMemsetAsync(sc, 0, 8, stream);

  const int nx4 = M * K / 4, nw4 = N * K / 4;
  nvfp4_amax_kernel<<<dim3(1024, 2), 256, 0, stream>>>(x, w, sc, nx4, nw4);

  nvfp4_quant_kernel<<<(nx4 + nw4 + 255) / 256, 256, 0, stream>>>(
      x, w, dx, dw, sc, nx4, nw4);

  nvfp4_gemm_kernel<<<dim3((M / BM) * (N / BN)), 512, 0, stream>>>(
      dx, dw, bias, sc, out, M, N, K);
}